// Round 1
// baseline (3102.492 us; speedup 1.0000x reference)
//
#include <hip/hip_runtime.h>
#include <hip/hip_bf16.h>
#include <math.h>

// Problem dims (fixed by reference)
#define BB 256
#define NN 5
#define DD 2048
#define CC 1000
#define HH 1024
#define PROTO_M 0.999f

// ---------------------------------------------------------------------------
// Y[b,n,d] = sum_m adj[n,m] * X[b,m,d]   (adj is 5x5), thread per (b,d)
// ---------------------------------------------------------------------------
__global__ void adj_mix_kernel(const float* __restrict__ adj,
                               const float* __restrict__ X,
                               float* __restrict__ Y, int Dd) {
    int idx = blockIdx.x * blockDim.x + threadIdx.x;
    int total = BB * Dd;
    if (idx >= total) return;
    int b = idx / Dd, d = idx % Dd;
    float xv[NN];
#pragma unroll
    for (int m = 0; m < NN; ++m)
        xv[m] = X[((size_t)b * NN + m) * Dd + d];
#pragma unroll
    for (int n = 0; n < NN; ++n) {
        float s = 0.f;
#pragma unroll
        for (int m = 0; m < NN; ++m) s += adj[n * NN + m] * xv[m];
        Y[((size_t)b * NN + n) * Dd + d] = s;
    }
}

// ---------------------------------------------------------------------------
// Tiled f32 GEMM: C[M,N] = A[M,K] @ B[K,N] (+bias) (+relu). Row-major.
// 256 threads, BMxBN tile, micro-tile (BM/16)x(BN/16) per thread.
// ---------------------------------------------------------------------------
template<int BM, int BN, int BK, bool RELU, bool BIAS>
__global__ __launch_bounds__(256) void gemm_f32(const float* __restrict__ A,
                                                const float* __restrict__ Bm,
                                                const float* __restrict__ bias,
                                                float* __restrict__ Cm,
                                                int M, int N, int K) {
    constexpr int TM = BM / 16, TN = BN / 16;
    __shared__ float As[BK][BM + 1];
    __shared__ float Bs[BK][BN + 1];
    const int tx = threadIdx.x % 16, ty = threadIdx.x / 16;
    const int m0 = blockIdx.y * BM, n0 = blockIdx.x * BN;
    float acc[TM][TN] = {};

    for (int k0 = 0; k0 < K; k0 += BK) {
        for (int i = threadIdx.x; i < BM * BK; i += 256) {
            int mi = i / BK, ki = i % BK;
            int m = m0 + mi, k = k0 + ki;
            As[ki][mi] = (m < M && k < K) ? A[(size_t)m * K + k] : 0.f;
        }
        for (int i = threadIdx.x; i < BK * BN; i += 256) {
            int ki = i / BN, ni = i % BN;
            int k = k0 + ki, n = n0 + ni;
            Bs[ki][ni] = (k < K && n < N) ? Bm[(size_t)k * N + n] : 0.f;
        }
        __syncthreads();
#pragma unroll
        for (int kk = 0; kk < BK; ++kk) {
            float a[TM], b[TN];
#pragma unroll
            for (int i = 0; i < TM; ++i) a[i] = As[kk][ty * TM + i];
#pragma unroll
            for (int j = 0; j < TN; ++j) b[j] = Bs[kk][tx * TN + j];
#pragma unroll
            for (int i = 0; i < TM; ++i)
#pragma unroll
                for (int j = 0; j < TN; ++j) acc[i][j] += a[i] * b[j];
        }
        __syncthreads();
    }

#pragma unroll
    for (int i = 0; i < TM; ++i) {
        int m = m0 + ty * TM + i;
        if (m >= M) continue;
#pragma unroll
        for (int j = 0; j < TN; ++j) {
            int n = n0 + tx * TN + j;
            if (n >= N) continue;
            float v = acc[i][j];
            if (BIAS) v += bias[n];
            if (RELU) v = fmaxf(v, 0.f);
            Cm[(size_t)m * N + n] = v;
        }
    }
}

// ---------------------------------------------------------------------------
// Per-sample rank (# later samples with same label) and per-class counts.
// Single block of 256 threads.
// ---------------------------------------------------------------------------
__global__ void rank_kernel(const int* __restrict__ target,
                            int* __restrict__ rank, int* __restrict__ cnt) {
    for (int c = threadIdx.x; c < CC; c += blockDim.x) cnt[c] = 0;
    __syncthreads();
    int b = threadIdx.x;
    int t = target[b];
    int r = 0;
    for (int b2 = b + 1; b2 < BB; ++b2) r += (target[b2] == t) ? 1 : 0;
    rank[b] = r;
    atomicAdd(&cnt[t], 1);
}

// out[c,n,d] = protos[c,n,d] * 0.999^cnt[c]
__global__ void proto_decay_kernel(const float* __restrict__ protos,
                                   const int* __restrict__ cnt,
                                   float* __restrict__ out) {
    int idx = blockIdx.x * blockDim.x + threadIdx.x;
    const int total = CC * NN * DD;
    if (idx >= total) return;
    int c = idx / (NN * DD);
    out[idx] = protos[idx] * powf(PROTO_M, (float)cnt[c]);
}

// out[target[b],n,d] += 0.001 * 0.999^rank[b] * x[b,n,d]
__global__ void proto_scatter_kernel(const float* __restrict__ x,
                                     const int* __restrict__ target,
                                     const int* __restrict__ rank,
                                     float* __restrict__ out) {
    int idx = blockIdx.x * blockDim.x + threadIdx.x;
    const int total = BB * NN * DD;
    if (idx >= total) return;
    int b = idx / (NN * DD);
    int nd = idx % (NN * DD);
    float coef = (1.0f - PROTO_M) * powf(PROTO_M, (float)rank[b]);
    atomicAdd(&out[(size_t)target[b] * NN * DD + nd], coef * x[idx]);
}

// in-place L2 normalize over node axis (axis=1 of [C,N,D])
__global__ void proto_norm_kernel(float* __restrict__ out) {
    int idx = blockIdx.x * blockDim.x + threadIdx.x;
    const int total = CC * DD;
    if (idx >= total) return;
    int c = idx / DD, d = idx % DD;
    size_t base = (size_t)c * NN * DD + d;
    float v[NN];
    float s = 0.f;
#pragma unroll
    for (int n = 0; n < NN; ++n) {
        v[n] = out[base + (size_t)n * DD];
        s += v[n] * v[n];
    }
    float norm = sqrtf(s);
    float inv = 1.0f / fmaxf(norm, 1e-12f);
#pragma unroll
    for (int n = 0; n < NN; ++n) out[base + (size_t)n * DD] = v[n] * inv;
}

// ---------------------------------------------------------------------------
extern "C" void kernel_launch(void* const* d_in, const int* in_sizes, int n_in,
                              void* d_out, int out_size, void* d_ws, size_t ws_size,
                              hipStream_t stream) {
    const float* x          = (const float*)d_in[0];
    const int*   target     = (const int*)d_in[1];
    const float* prototypes = (const float*)d_in[2];
    const float* adj        = (const float*)d_in[3];
    const float* W1         = (const float*)d_in[4];
    const float* W2         = (const float*)d_in[5];
    const float* Wg         = (const float*)d_in[6];
    const float* bg         = (const float*)d_in[7];
    const float* Wc         = (const float*)d_in[8];
    const float* bc         = (const float*)d_in[9];

    float* out_pred   = (float*)d_out;                    // [256,1000]
    float* out_protos = (float*)d_out + (size_t)BB * CC;  // [1000,5,2048]

    // workspace layout (floats)
    float* ax    = (float*)d_ws;                 // [1280,2048]
    float* h     = ax + (size_t)BB * NN * DD;    // [1280,1024]
    float* ah    = h + (size_t)BB * NN * HH;     // [1280,1024]
    float* nodes = ah + (size_t)BB * NN * HH;    // [1280,2048]
    float* g     = nodes + (size_t)BB * NN * DD; // [256,2048]
    int*   cnt   = (int*)(g + (size_t)BB * DD);  // [1000]
    int*   rank  = cnt + 1024;                   // [256]

    // ---- GCN path ----
    {
        int total = BB * DD;
        adj_mix_kernel<<<(total + 255) / 256, 256, 0, stream>>>(adj, x, ax, DD);
    }
    {
        dim3 grid(HH / 64, (BB * NN) / 64);
        gemm_f32<64, 64, 16, true, false><<<grid, 256, 0, stream>>>(
            ax, W1, nullptr, h, BB * NN, HH, DD);
    }
    {
        int total = BB * HH;
        adj_mix_kernel<<<(total + 255) / 256, 256, 0, stream>>>(adj, h, ah, HH);
    }
    {
        dim3 grid(DD / 64, (BB * NN) / 64);
        gemm_f32<64, 64, 16, false, false><<<grid, 256, 0, stream>>>(
            ah, W2, nullptr, nodes, BB * NN, DD, HH);
    }
    {
        dim3 grid(DD / 64, BB / 32);
        gemm_f32<32, 64, 16, false, true><<<grid, 256, 0, stream>>>(
            nodes, Wg, bg, g, BB, DD, NN * DD);
    }
    {
        dim3 grid((CC + 63) / 64, BB / 32);
        gemm_f32<32, 64, 16, false, true><<<grid, 256, 0, stream>>>(
            g, Wc, bc, out_pred, BB, CC, DD);
    }

    // ---- prototype EMA + normalize ----
    rank_kernel<<<1, 256, 0, stream>>>(target, rank, cnt);
    {
        int total = CC * NN * DD;
        proto_decay_kernel<<<(total + 255) / 256, 256, 0, stream>>>(
            prototypes, cnt, out_protos);
    }
    {
        int total = BB * NN * DD;
        proto_scatter_kernel<<<(total + 255) / 256, 256, 0, stream>>>(
            x, target, rank, out_protos);
    }
    {
        int total = CC * DD;
        proto_norm_kernel<<<(total + 255) / 256, 256, 0, stream>>>(out_protos);
    }
}

// Round 2
// 450.342 us; speedup vs baseline: 6.8892x; 6.8892x over previous
//
#include <hip/hip_runtime.h>
#include <hip/hip_bf16.h>
#include <math.h>

#define BB 256
#define NN 5
#define DD 2048
#define CC 1000
#define HH 1024
#define PROTO_M 0.999f

typedef unsigned short u16;
typedef __attribute__((ext_vector_type(8))) short short8;   // 8 bf16 (4 VGPRs)
typedef __attribute__((ext_vector_type(4))) float f32x4;

__device__ __forceinline__ u16 f2bf(float f) {
    union { float f; unsigned u; } x; x.f = f;
    unsigned r = x.u + 0x7fff + ((x.u >> 16) & 1);   // RNE
    return (u16)(r >> 16);
}
__device__ __forceinline__ float bf2f(u16 b) {
    union { unsigned u; float f; } x; x.u = ((unsigned)b) << 16;
    return x.f;
}

// ---------------------------------------------------------------------------
// Transpose + f32->bf16: in f32 [K][N] row-major -> out bf16 [N][K] row-major.
// 32x32 tiles via LDS (+1 pad). K multiple of 32; N guarded.
// ---------------------------------------------------------------------------
__global__ __launch_bounds__(256) void transpose_bf16(const float* __restrict__ in,
                                                      u16* __restrict__ out,
                                                      int K, int N) {
    __shared__ float tile[32][33];
    const int k0 = blockIdx.x * 32, n0 = blockIdx.y * 32;
    const int tr = threadIdx.x / 32, tc = threadIdx.x % 32;
#pragma unroll
    for (int i = 0; i < 4; ++i) {
        int r = i * 8 + tr;
        int n = n0 + tc;
        tile[r][tc] = (n < N) ? in[(size_t)(k0 + r) * N + n] : 0.f;
    }
    __syncthreads();
#pragma unroll
    for (int i = 0; i < 4; ++i) {
        int r = i * 8 + tr;                 // n-offset
        if (n0 + r < N)
            out[(size_t)(n0 + r) * K + k0 + tc] = f2bf(tile[tc][r]);
    }
}

// ---------------------------------------------------------------------------
// adj mix: Y[b,n,d] = sum_m adj[n,m] * X[b,m,d], bf16 output, float4-wide.
// ---------------------------------------------------------------------------
template<bool IN_BF16>
__global__ __launch_bounds__(256) void adj_mix(const float* __restrict__ adjp,
                                               const void* __restrict__ X,
                                               u16* __restrict__ Y, int Dd) {
    __shared__ float as_[NN * NN];
    if (threadIdx.x < NN * NN) as_[threadIdx.x] = adjp[threadIdx.x];
    __syncthreads();
    const int d4n = Dd / 4;
    int idx = blockIdx.x * blockDim.x + threadIdx.x;   // exact grid, no guard
    int b = idx / d4n, d4 = idx % d4n;
    float xv[NN][4];
#pragma unroll
    for (int m = 0; m < NN; ++m) {
        size_t base = ((size_t)b * NN + m) * Dd + d4 * 4;
        if (IN_BF16) {
            const ushort4 u = *(const ushort4*)((const u16*)X + base);
            xv[m][0] = bf2f(u.x); xv[m][1] = bf2f(u.y);
            xv[m][2] = bf2f(u.z); xv[m][3] = bf2f(u.w);
        } else {
            const float4 f = *(const float4*)((const float*)X + base);
            xv[m][0] = f.x; xv[m][1] = f.y; xv[m][2] = f.z; xv[m][3] = f.w;
        }
    }
#pragma unroll
    for (int n = 0; n < NN; ++n) {
        float s[4] = {0.f, 0.f, 0.f, 0.f};
#pragma unroll
        for (int m = 0; m < NN; ++m) {
            float a = as_[n * NN + m];
#pragma unroll
            for (int j = 0; j < 4; ++j) s[j] += a * xv[m][j];
        }
        ushort4 o;
        o.x = f2bf(s[0]); o.y = f2bf(s[1]); o.z = f2bf(s[2]); o.w = f2bf(s[3]);
        *(ushort4*)(Y + ((size_t)b * NN + n) * Dd + d4 * 4) = o;
    }
}

// ---------------------------------------------------------------------------
// bf16 MFMA GEMM: C[M,N] = A[M,K] @ Bt[N,K]^T. 256 thr = 4 waves (2x2).
// BK=32 (one 16x16x32 MFMA depth). Swizzled LDS (chunk ^= (row>>1)&3).
// ATOMIC: atomicAdd f32 partials (split-K). else: bf16 store (+optional relu).
// M must be multiple of BM; N guarded; K-span Ks multiple of 32.
// ---------------------------------------------------------------------------
template<int BM, int BN, bool ATOMIC, bool RELU>
__global__ __launch_bounds__(256) void gemm_mfma(const u16* __restrict__ A,
                                                 const u16* __restrict__ Bt,
                                                 void* __restrict__ C,
                                                 int M, int N, int K, int Ks) {
    constexpr int FM = BM / 32;       // frags per wave (m)
    constexpr int FN = BN / 32;       // frags per wave (n)
    __shared__ u16 As[BM * 32];
    __shared__ u16 Bs[BN * 32];
    const int t = threadIdx.x;
    const int lane = t & 63;
    const int wave = t >> 6;
    const int wr = wave >> 1, wc = wave & 1;
    const int lr = lane & 15;
    const int kc = lane >> 4;
    const int m0 = blockIdx.y * BM;
    const int n0 = blockIdx.x * BN;
    const int kz0 = blockIdx.z * Ks;
    const int srow = t >> 2;          // staging row 0..63
    const int sc = t & 3;             // staging k-chunk

    f32x4 acc[FM][FN];
#pragma unroll
    for (int i = 0; i < FM; ++i)
#pragma unroll
        for (int j = 0; j < FN; ++j) acc[i][j] = (f32x4){0.f, 0.f, 0.f, 0.f};

    const short8 zero8 = {0, 0, 0, 0, 0, 0, 0, 0};

    for (int k0 = kz0; k0 < kz0 + Ks; k0 += 32) {
        __syncthreads();
        // stage A (linear rows, swizzled chunk slot)
#pragma unroll
        for (int p = 0; p < BM / 64; ++p) {
            int row = p * 64 + srow;
            short8 v = *(const short8*)(A + (size_t)(m0 + row) * K + k0 + sc * 8);
            int ch = sc ^ ((row >> 1) & 3);
            *(short8*)(&As[row * 32 + ch * 8]) = v;
        }
        // stage Bt rows (cols of B), guarded on N
#pragma unroll
        for (int p = 0; p < BN / 64; ++p) {
            int row = p * 64 + srow;
            short8 v = zero8;
            if (n0 + row < N)
                v = *(const short8*)(Bt + (size_t)(n0 + row) * K + k0 + sc * 8);
            int ch = sc ^ ((row >> 1) & 3);
            *(short8*)(&Bs[row * 32 + ch * 8]) = v;
        }
        __syncthreads();

        short8 af[FM], bfr[FN];
#pragma unroll
        for (int i = 0; i < FM; ++i) {
            int row = wr * (BM / 2) + i * 16 + lr;
            int ch = kc ^ ((row >> 1) & 3);
            af[i] = *(const short8*)(&As[row * 32 + ch * 8]);
        }
#pragma unroll
        for (int j = 0; j < FN; ++j) {
            int row = wc * (BN / 2) + j * 16 + lr;
            int ch = kc ^ ((row >> 1) & 3);
            bfr[j] = *(const short8*)(&Bs[row * 32 + ch * 8]);
        }
#pragma unroll
        for (int i = 0; i < FM; ++i)
#pragma unroll
            for (int j = 0; j < FN; ++j)
                acc[i][j] = __builtin_amdgcn_mfma_f32_16x16x32_bf16(
                    af[i], bfr[j], acc[i][j], 0, 0, 0);
    }

    // epilogue: C/D layout col=lane&15, row=(lane>>4)*4+q  [m89-verified]
#pragma unroll
    for (int i = 0; i < FM; ++i) {
        int row = m0 + wr * (BM / 2) + i * 16 + kc * 4;
#pragma unroll
        for (int j = 0; j < FN; ++j) {
            int col = n0 + wc * (BN / 2) + j * 16 + lr;
            if (col >= N) continue;
#pragma unroll
            for (int q = 0; q < 4; ++q) {
                float v = acc[i][j][q];
                if (ATOMIC) {
                    atomicAdd((float*)C + (size_t)(row + q) * N + col, v);
                } else {
                    if (RELU) v = fmaxf(v, 0.f);
                    ((u16*)C)[(size_t)(row + q) * N + col] = f2bf(v);
                }
            }
        }
    }
}

// g_bf16 = bf16(g_f32 + bg), float4-wide (N=2048)
__global__ __launch_bounds__(256) void finalize_g(const float* __restrict__ gf,
                                                  const float* __restrict__ bg,
                                                  u16* __restrict__ gb) {
    int idx = blockIdx.x * blockDim.x + threadIdx.x;   // BB*DD/4, exact
    int n4 = idx % (DD / 4);
    float4 v = *(const float4*)(gf + (size_t)idx * 4);
    float4 b = *(const float4*)(bg + n4 * 4);
    ushort4 o;
    o.x = f2bf(v.x + b.x); o.y = f2bf(v.y + b.y);
    o.z = f2bf(v.z + b.z); o.w = f2bf(v.w + b.w);
    *(ushort4*)(gb + (size_t)idx * 4) = o;
}

// out_pred = pred_f32 + bc  (N=1000, 250 float4 per row)
__global__ __launch_bounds__(256) void finalize_pred(const float* __restrict__ pf,
                                                     const float* __restrict__ bc,
                                                     float* __restrict__ out) {
    int idx = blockIdx.x * blockDim.x + threadIdx.x;   // BB*250, exact
    int n4 = idx % 250;
    float4 v = *(const float4*)(pf + (size_t)idx * 4);
    float4 b = *(const float4*)(bc + n4 * 4);
    float4 o; o.x = v.x + b.x; o.y = v.y + b.y; o.z = v.z + b.z; o.w = v.w + b.w;
    *(float4*)(out + (size_t)idx * 4) = o;
}

// ---------------------------------------------------------------------------
// Prototype EMA closed form + L2 normalize
// ---------------------------------------------------------------------------
__global__ void rank_kernel(const int* __restrict__ target,
                            int* __restrict__ rank, int* __restrict__ cnt) {
    for (int c = threadIdx.x; c < CC; c += blockDim.x) cnt[c] = 0;
    __syncthreads();
    int b = threadIdx.x;
    int tt = target[b];
    int r = 0;
    for (int b2 = b + 1; b2 < BB; ++b2) r += (target[b2] == tt) ? 1 : 0;
    rank[b] = r;
    atomicAdd(&cnt[tt], 1);
}

__global__ __launch_bounds__(256) void proto_decay(const float* __restrict__ protos,
                                                   const int* __restrict__ cnt,
                                                   float* __restrict__ out) {
    int idx = blockIdx.x * blockDim.x + threadIdx.x;   // CC*NN*DD/4, exact
    int c = idx / (NN * DD / 4);
    float s = powf(PROTO_M, (float)cnt[c]);
    float4 v = *(const float4*)(protos + (size_t)idx * 4);
    v.x *= s; v.y *= s; v.z *= s; v.w *= s;
    *(float4*)(out + (size_t)idx * 4) = v;
}

__global__ __launch_bounds__(256) void proto_scatter(const float* __restrict__ x,
                                                     const int* __restrict__ target,
                                                     const int* __restrict__ rank,
                                                     float* __restrict__ out) {
    int idx = blockIdx.x * blockDim.x + threadIdx.x;   // BB*NN*DD/4, exact
    int b = idx / (NN * DD / 4);
    int nd4 = idx % (NN * DD / 4);
    float coef = (1.0f - PROTO_M) * powf(PROTO_M, (float)rank[b]);
    float4 v = *(const float4*)(x + (size_t)idx * 4);
    float* dst = out + (size_t)target[b] * NN * DD + nd4 * 4;
    atomicAdd(dst + 0, coef * v.x);
    atomicAdd(dst + 1, coef * v.y);
    atomicAdd(dst + 2, coef * v.z);
    atomicAdd(dst + 3, coef * v.w);
}

__global__ __launch_bounds__(256) void proto_norm(float* __restrict__ out) {
    int idx = blockIdx.x * blockDim.x + threadIdx.x;   // CC*DD/4, exact
    int c = idx / (DD / 4), d4 = idx % (DD / 4);
    size_t base = (size_t)c * NN * DD + d4 * 4;
    float4 v[NN];
    float s[4] = {0.f, 0.f, 0.f, 0.f};
#pragma unroll
    for (int n = 0; n < NN; ++n) {
        v[n] = *(const float4*)(out + base + (size_t)n * DD);
        s[0] += v[n].x * v[n].x; s[1] += v[n].y * v[n].y;
        s[2] += v[n].z * v[n].z; s[3] += v[n].w * v[n].w;
    }
    float inv[4];
#pragma unroll
    for (int j = 0; j < 4; ++j) inv[j] = 1.0f / fmaxf(sqrtf(s[j]), 1e-12f);
#pragma unroll
    for (int n = 0; n < NN; ++n) {
        float4 o; o.x = v[n].x * inv[0]; o.y = v[n].y * inv[1];
        o.z = v[n].z * inv[2]; o.w = v[n].w * inv[3];
        *(float4*)(out + base + (size_t)n * DD) = o;
    }
}

// ---------------------------------------------------------------------------
extern "C" void kernel_launch(void* const* d_in, const int* in_sizes, int n_in,
                              void* d_out, int out_size, void* d_ws, size_t ws_size,
                              hipStream_t stream) {
    const float* x          = (const float*)d_in[0];
    const int*   target     = (const int*)d_in[1];
    const float* prototypes = (const float*)d_in[2];
    const float* adj        = (const float*)d_in[3];
    const float* W1         = (const float*)d_in[4];
    const float* W2         = (const float*)d_in[5];
    const float* Wg         = (const float*)d_in[6];
    const float* bg         = (const float*)d_in[7];
    const float* Wc         = (const float*)d_in[8];
    const float* bc         = (const float*)d_in[9];

    float* out_pred   = (float*)d_out;                    // [256,1000]
    float* out_protos = (float*)d_out + (size_t)BB * CC;  // [1000,5,2048]

    // ---- workspace layout (16B-aligned partitions) ----
    char* w = (char*)d_ws;
    u16* Wgt     = (u16*)w;                 w += (size_t)DD * NN * DD * 2;      // 40MB [2048][10240]
    u16* Wt      = (u16*)w;                 w += (size_t)DD * HH * 2 * 2;       // 8MB shared W1t/W2t/Wct (padded)
    u16* ax      = (u16*)w;                 w += (size_t)BB * NN * DD * 2;      // 5MB (also nodes)
    u16* nodes   = ax;                                                          // reuse after G1
    u16* h       = (u16*)w;                 w += (size_t)BB * NN * HH * 2;      // 2.5MB
    u16* ah      = (u16*)w;                 w += (size_t)BB * NN * HH * 2;      // 2.5MB
    float* g_f32 = (float*)w;               w += (size_t)BB * DD * 4;           // 2MB
    u16* g_bf16  = (u16*)w;                 w += (size_t)BB * DD * 2;           // 1MB
    float* pred_f32 = (float*)w;            w += (size_t)BB * CC * 4;           // 1MB (250 f4/row)
    int* cnt     = (int*)w;                 w += 1024 * 4;
    int* rank    = (int*)w;                 w += 256 * 4;

    // ---- GCN path (bf16 MFMA) ----
    // W1t [1024][2048]
    transpose_bf16<<<dim3(DD / 32, HH / 32), 256, 0, stream>>>(W1, Wt, DD, HH);
    // ax = adj (x) x, bf16
    adj_mix<false><<<(BB * DD / 4) / 256, 256, 0, stream>>>(adj, x, ax, DD);
    // G1: h = relu(ax @ W1)  [1280,1024]
    gemm_mfma<128, 64, false, true><<<dim3(HH / 64, (BB * NN) / 128, 1), 256, 0, stream>>>(
        ax, Wt, h, BB * NN, HH, DD, DD);
    // ah = adj (x) h
    adj_mix<true><<<(BB * HH / 4) / 256, 256, 0, stream>>>(adj, h, ah, HH);
    // W2t [2048][1024]
    transpose_bf16<<<dim3(HH / 32, DD / 32), 256, 0, stream>>>(W2, Wt, HH, DD);
    // G2: nodes = ah @ W2  [1280,2048]
    gemm_mfma<128, 128, false, false><<<dim3(DD / 128, (BB * NN) / 128, 1), 256, 0, stream>>>(
        ah, Wt, nodes, BB * NN, DD, HH, HH);
    // Wgt [2048][10240]
    transpose_bf16<<<dim3((NN * DD) / 32, DD / 32), 256, 0, stream>>>(Wg, Wgt, NN * DD, DD);
    // G3 (fc_g): g_f32 += nodes.reshape(256,10240) @ Wg, split-K=8
    hipMemsetAsync(g_f32, 0, (size_t)BB * DD * 4, stream);
    gemm_mfma<128, 128, true, false><<<dim3(DD / 128, BB / 128, 8), 256, 0, stream>>>(
        nodes, Wgt, g_f32, BB, DD, NN * DD, NN * DD / 8);
    finalize_g<<<(BB * DD / 4) / 256, 256, 0, stream>>>(g_f32, bg, g_bf16);
    // Wct [1000][2048]
    transpose_bf16<<<dim3(DD / 32, (CC + 31) / 32), 256, 0, stream>>>(Wc, Wt, DD, CC);
    // G4 (fc_cls): pred_f32 += g @ Wc, split-K=2
    hipMemsetAsync(pred_f32, 0, (size_t)BB * CC * 4, stream);
    gemm_mfma<128, 64, true, false><<<dim3((CC + 63) / 64, BB / 128, 2), 256, 0, stream>>>(
        g_bf16, Wt, pred_f32, BB, CC, DD, DD / 2);
    finalize_pred<<<(BB * 250) / 256, 256, 0, stream>>>(pred_f32, bc, out_pred);

    // ---- prototype EMA + normalize (exact f32) ----
    rank_kernel<<<1, 256, 0, stream>>>(target, rank, cnt);
    proto_decay<<<(CC * NN * DD / 4) / 256, 256, 0, stream>>>(prototypes, cnt, out_protos);
    proto_scatter<<<(BB * NN * DD / 4) / 256, 256, 0, stream>>>(x, target, rank, out_protos);
    proto_norm<<<(CC * DD / 4) / 256, 256, 0, stream>>>(out_protos);
}

// Round 3
// 338.158 us; speedup vs baseline: 9.1747x; 1.3318x over previous
//
#include <hip/hip_runtime.h>
#include <hip/hip_bf16.h>
#include <math.h>

#define BB 256
#define NN 5
#define DD 2048
#define CC 1000
#define HH 1024
#define PROTO_M 0.999f

typedef unsigned short u16;
typedef __attribute__((ext_vector_type(8))) short short8;   // 8 bf16
typedef __attribute__((ext_vector_type(4))) float f32x4;

__device__ __forceinline__ u16 f2bf(float f) {
    union { float f; unsigned u; } x; x.f = f;
    unsigned r = x.u + 0x7fff + ((x.u >> 16) & 1);   // RNE
    return (u16)(r >> 16);
}
__device__ __forceinline__ float bf2f(u16 b) {
    union { unsigned u; float f; } x; x.u = ((unsigned)b) << 16;
    return x.f;
}

// ---------------------------------------------------------------------------
// Fast transpose + f32->bf16: in f32 [K][N] -> out bf16 [N][K].
// 64x64 tile. Loads float4 (coalesced rows), LDS transposed store (u16,
// stride 72 keeps ushort8 reads 16B-aligned), stores ushort8 (128B segments).
// K multiple of 64, N multiple of 4; N guarded.
// ---------------------------------------------------------------------------
__global__ __launch_bounds__(256) void transpose_bf16(const float* __restrict__ in,
                                                      u16* __restrict__ out,
                                                      int K, int N) {
    constexpr int STR = 72;                  // u16 stride per n-row (16B aligned)
    __shared__ u16 T[64 * STR];
    const int k0 = blockIdx.x * 64, n0 = blockIdx.y * 64;
    const int t = threadIdx.x;
    const int c4 = t % 16;                   // n-quad 0..15
    const int rr = t / 16;                   // k-row 0..15
#pragma unroll
    for (int p = 0; p < 4; ++p) {
        int k = p * 16 + rr;
        int n = c4 * 4;
        if (n0 + n < N) {
            float4 v = *(const float4*)(in + (size_t)(k0 + k) * N + n0 + n);
            T[(n + 0) * STR + k] = f2bf(v.x);
            T[(n + 1) * STR + k] = f2bf(v.y);
            T[(n + 2) * STR + k] = f2bf(v.z);
            T[(n + 3) * STR + k] = f2bf(v.w);
        }
    }
    __syncthreads();
    const int ch = t % 8;                    // k-chunk of 8
    const int nl0 = t / 8;                   // 0..31
#pragma unroll
    for (int q = 0; q < 2; ++q) {
        int nl = nl0 + q * 32;
        if (n0 + nl < N) {
            short8 v = *(const short8*)(&T[nl * STR + ch * 8]);
            *(short8*)(out + (size_t)(n0 + nl) * K + k0 + ch * 8) = v;
        }
    }
}

// ---------------------------------------------------------------------------
// adj mix: Y[b,n,d] = sum_m adj[n,m] * X[b,m,d], bf16 output, float4-wide.
// ---------------------------------------------------------------------------
template<bool IN_BF16>
__global__ __launch_bounds__(256) void adj_mix(const float* __restrict__ adjp,
                                               const void* __restrict__ X,
                                               u16* __restrict__ Y, int Dd) {
    __shared__ float as_[NN * NN];
    if (threadIdx.x < NN * NN) as_[threadIdx.x] = adjp[threadIdx.x];
    __syncthreads();
    const int d4n = Dd / 4;
    int idx = blockIdx.x * blockDim.x + threadIdx.x;   // exact grid
    int b = idx / d4n, d4 = idx % d4n;
    float xv[NN][4];
#pragma unroll
    for (int m = 0; m < NN; ++m) {
        size_t base = ((size_t)b * NN + m) * Dd + d4 * 4;
        if (IN_BF16) {
            const ushort4 u = *(const ushort4*)((const u16*)X + base);
            xv[m][0] = bf2f(u.x); xv[m][1] = bf2f(u.y);
            xv[m][2] = bf2f(u.z); xv[m][3] = bf2f(u.w);
        } else {
            const float4 f = *(const float4*)((const float*)X + base);
            xv[m][0] = f.x; xv[m][1] = f.y; xv[m][2] = f.z; xv[m][3] = f.w;
        }
    }
#pragma unroll
    for (int n = 0; n < NN; ++n) {
        float s[4] = {0.f, 0.f, 0.f, 0.f};
#pragma unroll
        for (int m = 0; m < NN; ++m) {
            float a = as_[n * NN + m];
#pragma unroll
            for (int j = 0; j < 4; ++j) s[j] += a * xv[m][j];
        }
        ushort4 o;
        o.x = f2bf(s[0]); o.y = f2bf(s[1]); o.z = f2bf(s[2]); o.w = f2bf(s[3]);
        *(ushort4*)(Y + ((size_t)b * NN + n) * Dd + d4 * 4) = o;
    }
}

// ---------------------------------------------------------------------------
// bf16 MFMA GEMM, double-buffered prefetch (2-phase):
//   iter t: issue global loads for tile t+1 -> barrier -> ds_read+MFMA(t)
//           -> barrier -> ds_write tile t+1. Load latency hides under MFMA.
// C[M,N] = A[M,K] @ Bt[N,K]^T. 256 thr = 4 waves (2x2). BK=32.
// Chunk-XOR LDS swizzle (ch ^= (row>>1)&3). M % BM == 0; N guarded.
// ---------------------------------------------------------------------------
template<int BM, int BN, bool ATOMIC, bool RELU>
__global__ __launch_bounds__(256) void gemm_mfma(const u16* __restrict__ A,
                                                 const u16* __restrict__ Bt,
                                                 void* __restrict__ C,
                                                 int M, int N, int K, int Ks) {
    constexpr int FM = BM / 32;
    constexpr int FN = BN / 32;
    constexpr int PA = BM / 64;
    constexpr int PB = BN / 64;
    __shared__ u16 As[2 * BM * 32];
    __shared__ u16 Bs[2 * BN * 32];
    const int t = threadIdx.x;
    const int lane = t & 63;
    const int wave = t >> 6;
    const int wr = wave >> 1, wc = wave & 1;
    const int lr = lane & 15;
    const int kc = lane >> 4;
    const int m0 = blockIdx.y * BM;
    const int n0 = blockIdx.x * BN;
    const int kz0 = blockIdx.z * Ks;
    const int srow = t >> 2;
    const int sc = t & 3;

    f32x4 acc[FM][FN];
#pragma unroll
    for (int i = 0; i < FM; ++i)
#pragma unroll
        for (int j = 0; j < FN; ++j) acc[i][j] = (f32x4){0.f, 0.f, 0.f, 0.f};

    const short8 zero8 = {0, 0, 0, 0, 0, 0, 0, 0};
    short8 ra[PA], rb[PB];

    auto LOAD = [&](int k0) {
#pragma unroll
        for (int p = 0; p < PA; ++p) {
            int row = p * 64 + srow;
            ra[p] = *(const short8*)(A + (size_t)(m0 + row) * K + k0 + sc * 8);
        }
#pragma unroll
        for (int p = 0; p < PB; ++p) {
            int row = p * 64 + srow;
            rb[p] = (n0 + row < N)
                ? *(const short8*)(Bt + (size_t)(n0 + row) * K + k0 + sc * 8)
                : zero8;
        }
    };
    auto WRITE = [&](int buf) {
#pragma unroll
        for (int p = 0; p < PA; ++p) {
            int row = p * 64 + srow;
            int ch = sc ^ ((row >> 1) & 3);
            *(short8*)(&As[buf * BM * 32 + row * 32 + ch * 8]) = ra[p];
        }
#pragma unroll
        for (int p = 0; p < PB; ++p) {
            int row = p * 64 + srow;
            int ch = sc ^ ((row >> 1) & 3);
            *(short8*)(&Bs[buf * BN * 32 + row * 32 + ch * 8]) = rb[p];
        }
    };

    const int nt = Ks / 32;
    LOAD(kz0);
    WRITE(0);
    for (int tt = 0; tt < nt; ++tt) {
        if (tt + 1 < nt) LOAD(kz0 + (tt + 1) * 32);
        __syncthreads();                       // buf[tt&1] writes visible
        const int buf = tt & 1;
        short8 af[FM], bfr[FN];
#pragma unroll
        for (int i = 0; i < FM; ++i) {
            int row = wr * (BM / 2) + i * 16 + lr;
            int ch = kc ^ ((row >> 1) & 3);
            af[i] = *(const short8*)(&As[buf * BM * 32 + row * 32 + ch * 8]);
        }
#pragma unroll
        for (int j = 0; j < FN; ++j) {
            int row = wc * (BN / 2) + j * 16 + lr;
            int ch = kc ^ ((row >> 1) & 3);
            bfr[j] = *(const short8*)(&Bs[buf * BN * 32 + row * 32 + ch * 8]);
        }
#pragma unroll
        for (int i = 0; i < FM; ++i)
#pragma unroll
            for (int j = 0; j < FN; ++j)
                acc[i][j] = __builtin_amdgcn_mfma_f32_16x16x32_bf16(
                    af[i], bfr[j], acc[i][j], 0, 0, 0);
        __syncthreads();                       // all reads of buf^1 done
        if (tt + 1 < nt) WRITE((tt + 1) & 1);
    }

    // epilogue: C/D layout col=lane&15, row=(lane>>4)*4+q
#pragma unroll
    for (int i = 0; i < FM; ++i) {
        int row = m0 + wr * (BM / 2) + i * 16 + kc * 4;
#pragma unroll
        for (int j = 0; j < FN; ++j) {
            int col = n0 + wc * (BN / 2) + j * 16 + lr;
            if (col >= N) continue;
#pragma unroll
            for (int q = 0; q < 4; ++q) {
                float v = acc[i][j][q];
                if (ATOMIC) {
                    atomicAdd((float*)C + (size_t)(row + q) * N + col, v);
                } else {
                    if (RELU) v = fmaxf(v, 0.f);
                    ((u16*)C)[(size_t)(row + q) * N + col] = f2bf(v);
                }
            }
        }
    }
}

// g_bf16 = bf16(g_f32 + bg)
__global__ __launch_bounds__(256) void finalize_g(const float* __restrict__ gf,
                                                  const float* __restrict__ bg,
                                                  u16* __restrict__ gb) {
    int idx = blockIdx.x * blockDim.x + threadIdx.x;
    int n4 = idx % (DD / 4);
    float4 v = *(const float4*)(gf + (size_t)idx * 4);
    float4 b = *(const float4*)(bg + n4 * 4);
    ushort4 o;
    o.x = f2bf(v.x + b.x); o.y = f2bf(v.y + b.y);
    o.z = f2bf(v.z + b.z); o.w = f2bf(v.w + b.w);
    *(ushort4*)(gb + (size_t)idx * 4) = o;
}

// out_pred = pred_f32 + bc
__global__ __launch_bounds__(256) void finalize_pred(const float* __restrict__ pf,
                                                     const float* __restrict__ bc,
                                                     float* __restrict__ out) {
    int idx = blockIdx.x * blockDim.x + threadIdx.x;
    int n4 = idx % 250;
    float4 v = *(const float4*)(pf + (size_t)idx * 4);
    float4 b = *(const float4*)(bc + n4 * 4);
    float4 o; o.x = v.x + b.x; o.y = v.y + b.y; o.z = v.z + b.z; o.w = v.w + b.w;
    *(float4*)(out + (size_t)idx * 4) = o;
}

// ---------------------------------------------------------------------------
// Rank/scan: per-class counts, exclusive starts, class-sorted sample order
// (stable by b), per-slot EMA coefficient, per-class decay. One 1024 block.
// ---------------------------------------------------------------------------
__global__ __launch_bounds__(1024) void rank_build(const int* __restrict__ target,
                                                   int* __restrict__ cnt,
                                                   int* __restrict__ start,
                                                   int* __restrict__ order,
                                                   float* __restrict__ coef,
                                                   float* __restrict__ decayc) {
    __shared__ int stgt[BB];
    __shared__ int scnt[1024];
    __shared__ int sscan[1024];
    const int t = threadIdx.x;
    scnt[t] = 0;
    if (t < BB) stgt[t] = target[t];
    __syncthreads();
    int myc = -1, posc = 0;
    if (t < BB) {
        myc = stgt[t];
        for (int b2 = 0; b2 < t; ++b2) posc += (stgt[b2] == myc) ? 1 : 0;
        atomicAdd(&scnt[myc], 1);
    }
    __syncthreads();
    sscan[t] = scnt[t];
    __syncthreads();
    for (int off = 1; off < 1024; off <<= 1) {
        int add = (t >= off) ? sscan[t - off] : 0;
        __syncthreads();
        sscan[t] += add;
        __syncthreads();
    }
    if (t < CC) {
        cnt[t] = scnt[t];
        start[t] = sscan[t] - scnt[t];
        decayc[t] = powf(PROTO_M, (float)scnt[t]);
    }
    __syncthreads();
    if (t < BB) {
        int s = sscan[myc] - scnt[myc];
        order[s + posc] = t;
        coef[s + posc] = (1.0f - PROTO_M) * powf(PROTO_M, (float)(scnt[myc] - 1 - posc));
    }
}

// ---------------------------------------------------------------------------
// Fused prototype update: out[c] = normalize(protos[c]*decay[c] + sum_j
// coef_j * x[order_j]) over node axis. Block covers one (c, half-of-D).
// ---------------------------------------------------------------------------
__global__ __launch_bounds__(256) void proto_fused(const float* __restrict__ protos,
                                                   const float* __restrict__ x,
                                                   const int* __restrict__ cnt,
                                                   const int* __restrict__ start,
                                                   const int* __restrict__ order,
                                                   const float* __restrict__ coef,
                                                   const float* __restrict__ decayc,
                                                   float* __restrict__ out) {
    const int c = blockIdx.x >> 1;
    const int d = ((blockIdx.x & 1) * 256 + threadIdx.x) * 4;   // 0..2044
    const float dec = decayc[c];
    const int k = cnt[c];
    const int s = start[c];
    float4 v[NN];
#pragma unroll
    for (int n = 0; n < NN; ++n) {
        float4 p = *(const float4*)(protos + ((size_t)c * NN + n) * DD + d);
        v[n].x = p.x * dec; v[n].y = p.y * dec; v[n].z = p.z * dec; v[n].w = p.w * dec;
    }
    for (int j = 0; j < k; ++j) {
        int b = order[s + j];
        float cf = coef[s + j];
#pragma unroll
        for (int n = 0; n < NN; ++n) {
            float4 xv = *(const float4*)(x + ((size_t)b * NN + n) * DD + d);
            v[n].x += cf * xv.x; v[n].y += cf * xv.y;
            v[n].z += cf * xv.z; v[n].w += cf * xv.w;
        }
    }
    float ss[4] = {0.f, 0.f, 0.f, 0.f};
#pragma unroll
    for (int n = 0; n < NN; ++n) {
        ss[0] += v[n].x * v[n].x; ss[1] += v[n].y * v[n].y;
        ss[2] += v[n].z * v[n].z; ss[3] += v[n].w * v[n].w;
    }
    float inv[4];
#pragma unroll
    for (int j = 0; j < 4; ++j) inv[j] = 1.0f / fmaxf(sqrtf(ss[j]), 1e-12f);
#pragma unroll
    for (int n = 0; n < NN; ++n) {
        float4 o;
        o.x = v[n].x * inv[0]; o.y = v[n].y * inv[1];
        o.z = v[n].z * inv[2]; o.w = v[n].w * inv[3];
        *(float4*)(out + ((size_t)c * NN + n) * DD + d) = o;
    }
}

// ---------------------------------------------------------------------------
extern "C" void kernel_launch(void* const* d_in, const int* in_sizes, int n_in,
                              void* d_out, int out_size, void* d_ws, size_t ws_size,
                              hipStream_t stream) {
    const float* x          = (const float*)d_in[0];
    const int*   target     = (const int*)d_in[1];
    const float* prototypes = (const float*)d_in[2];
    const float* adj        = (const float*)d_in[3];
    const float* W1         = (const float*)d_in[4];
    const float* W2         = (const float*)d_in[5];
    const float* Wg         = (const float*)d_in[6];
    const float* bg         = (const float*)d_in[7];
    const float* Wc         = (const float*)d_in[8];
    const float* bc         = (const float*)d_in[9];

    float* out_pred   = (float*)d_out;                    // [256,1000]
    float* out_protos = (float*)d_out + (size_t)BB * CC;  // [1000,5,2048]

    // ---- workspace layout ----
    char* w = (char*)d_ws;
    u16* Wgt     = (u16*)w;                 w += (size_t)DD * NN * DD * 2;  // 40MB [2048][10240]
    u16* Wt      = (u16*)w;                 w += (size_t)DD * HH * 2 * 2;   // 8MB shared W1t/W2t/Wct
    u16* ax      = (u16*)w;                 w += (size_t)BB * NN * DD * 2;  // 5MB
    u16* nodes   = ax;                                                      // reuse after G1
    u16* h       = (u16*)w;                 w += (size_t)BB * NN * HH * 2;  // 2.5MB
    u16* ah      = (u16*)w;                 w += (size_t)BB * NN * HH * 2;  // 2.5MB
    float* g_f32 = (float*)w;               w += (size_t)BB * DD * 4;       // 2MB
    u16* g_bf16  = (u16*)w;                 w += (size_t)BB * DD * 2;       // 1MB
    float* pred_f32 = (float*)w;            w += (size_t)BB * CC * 4;       // 1MB
    int* cnt     = (int*)w;                 w += 1024 * 4;
    int* start   = (int*)w;                 w += 1024 * 4;
    int* order   = (int*)w;                 w += 256 * 4;
    float* coef  = (float*)w;               w += 256 * 4;
    float* decayc= (float*)w;               w += 1024 * 4;

    // ---- GCN path (bf16 MFMA) ----
    transpose_bf16<<<dim3(DD / 64, HH / 64), 256, 0, stream>>>(W1, Wt, DD, HH);
    adj_mix<false><<<(BB * DD / 4) / 256, 256, 0, stream>>>(adj, x, ax, DD);
    // G1: h = relu(ax @ W1)  [1280,1024]  grid 16x20=320
    gemm_mfma<64, 64, false, true><<<dim3(HH / 64, (BB * NN) / 64, 1), 256, 0, stream>>>(
        ax, Wt, h, BB * NN, HH, DD, DD);
    adj_mix<true><<<(BB * HH / 4) / 256, 256, 0, stream>>>(adj, h, ah, HH);
    transpose_bf16<<<dim3(HH / 64, DD / 64), 256, 0, stream>>>(W2, Wt, HH, DD);
    // G2: nodes = ah @ W2  [1280,2048]  grid 32x20=640
    gemm_mfma<64, 64, false, false><<<dim3(DD / 64, (BB * NN) / 64, 1), 256, 0, stream>>>(
        ah, Wt, nodes, BB * NN, DD, HH, HH);
    transpose_bf16<<<dim3((NN * DD) / 64, DD / 64), 256, 0, stream>>>(Wg, Wgt, NN * DD, DD);
    // G3 (fc_g): split-K=8, grid 16x2x8=256
    hipMemsetAsync(g_f32, 0, (size_t)BB * DD * 4, stream);
    gemm_mfma<128, 128, true, false><<<dim3(DD / 128, BB / 128, 8), 256, 0, stream>>>(
        nodes, Wgt, g_f32, BB, DD, NN * DD, NN * DD / 8);
    finalize_g<<<(BB * DD / 4) / 256, 256, 0, stream>>>(g_f32, bg, g_bf16);
    transpose_bf16<<<dim3(DD / 64, (CC + 63) / 64), 256, 0, stream>>>(Wc, Wt, DD, CC);
    // G4 (fc_cls): split-K=8, grid 16x2x8=256
    hipMemsetAsync(pred_f32, 0, (size_t)BB * CC * 4, stream);
    gemm_mfma<128, 64, true, false><<<dim3((CC + 63) / 64, BB / 128, 8), 256, 0, stream>>>(
        g_bf16, Wt, pred_f32, BB, CC, DD, DD / 8);
    finalize_pred<<<(BB * 250) / 256, 256, 0, stream>>>(pred_f32, bc, out_pred);

    // ---- prototype EMA + normalize (exact f32, fused) ----
    rank_build<<<1, 1024, 0, stream>>>(target, cnt, start, order, coef, decayc);
    proto_fused<<<CC * 2, 256, 0, stream>>>(prototypes, x, cnt, start, order,
                                            coef, decayc, out_protos);
}